// Round 1
// baseline (1503.513 us; speedup 1.0000x reference)
//
#include <hip/hip_runtime.h>

// GCN1: 2-layer GCN, N=500000 nodes, E=8,000,000 edges, features 1 -> 32 -> 2.
// Key algebraic reductions:
//   * Layer 1: x is [N,1] so h1[i,f] = relu(s[i]*W1[f] + b1[f]) where s[i] is a
//     SCALAR normalized aggregate. Only one float scatter-add per edge.
//   * Layer 2: only the 2-dim y[i,:] = h1[i,:] @ W2 needs aggregation.
// Sym-norm: deg = in-degree incl self-loop (>=1), dinv = rsqrt(deg),
//   norm_e = dinv[src]*dinv[dst]. Factor dinv[dst] out of the segment sum.

static constexpr int NT = 256;
static constexpr int MAX_EDGE_BLK = 2048;

// ---------------- init: deg=1 (self loop), accA=0, accB=0 ----------------
__global__ void k_init(unsigned* __restrict__ deg, float* __restrict__ accA,
                       float2* __restrict__ accB, int n) {
  int stride = gridDim.x * blockDim.x;
  for (int i = blockIdx.x * blockDim.x + threadIdx.x; i < n; i += stride) {
    deg[i] = 1u;
    accA[i] = 0.0f;
    accB[i] = make_float2(0.0f, 0.0f);
  }
}

// ---------------- degree: deg[dst] += 1 over all edges ----------------
__global__ void k_degree(const int* __restrict__ dst, int e4, int e,
                         unsigned* __restrict__ deg) {
  int stride = gridDim.x * blockDim.x;
  const int4* d4 = (const int4*)dst;
  int tid = blockIdx.x * blockDim.x + threadIdx.x;
  for (int i = tid; i < e4; i += stride) {
    int4 d = d4[i];
    atomicAdd(deg + d.x, 1u);
    atomicAdd(deg + d.y, 1u);
    atomicAdd(deg + d.z, 1u);
    atomicAdd(deg + d.w, 1u);
  }
  for (int i = e4 * 4 + tid; i < e; i += stride)  // tail (E%4)
    atomicAdd(deg + dst[i], 1u);
}

// ---------------- node1: dinv = rsqrt(deg); xs = dinv*x ----------------
__global__ void k_node1(const unsigned* __restrict__ deg, const float* __restrict__ x,
                        float* __restrict__ dinv, float* __restrict__ xs, int n) {
  int stride = gridDim.x * blockDim.x;
  for (int i = blockIdx.x * blockDim.x + threadIdx.x; i < n; i += stride) {
    float di = rsqrtf((float)deg[i]);
    dinv[i] = di;
    xs[i] = di * x[i];
  }
}

// ---------------- pass A: accA[dst] += xs[src] (scalar) ----------------
__global__ void k_passA(const int* __restrict__ src, const int* __restrict__ dst,
                        int e4, int e, const float* __restrict__ xs,
                        float* __restrict__ accA) {
  int stride = gridDim.x * blockDim.x;
  const int4* s4 = (const int4*)src;
  const int4* d4 = (const int4*)dst;
  int tid = blockIdx.x * blockDim.x + threadIdx.x;
  for (int i = tid; i < e4; i += stride) {
    int4 s = s4[i];
    int4 d = d4[i];
    unsafeAtomicAdd(accA + d.x, xs[s.x]);
    unsafeAtomicAdd(accA + d.y, xs[s.y]);
    unsafeAtomicAdd(accA + d.z, xs[s.z]);
    unsafeAtomicAdd(accA + d.w, xs[s.w]);
  }
  for (int i = e4 * 4 + tid; i < e; i += stride)
    unsafeAtomicAdd(accA + dst[i], xs[src[i]]);
}

// ------- node2: s -> h1[32] -> y[2]; store yd = dinv*y (float2) -------
__global__ void k_node2(const float* __restrict__ dinv, const float* __restrict__ xs,
                        const float* __restrict__ accA,
                        const float* __restrict__ W1, const float* __restrict__ b1,
                        const float* __restrict__ W2,
                        float2* __restrict__ yd, int n) {
  __shared__ float sW1[32], sb1[32], sW2[64];
  if (threadIdx.x < 32) {
    sW1[threadIdx.x] = W1[threadIdx.x];
    sb1[threadIdx.x] = b1[threadIdx.x];
  }
  if (threadIdx.x < 64) sW2[threadIdx.x] = W2[threadIdx.x];
  __syncthreads();
  int stride = gridDim.x * blockDim.x;
  for (int i = blockIdx.x * blockDim.x + threadIdx.x; i < n; i += stride) {
    float di = dinv[i];
    // self-loop contributes dinv^2 * x = dinv * xs
    float s = di * (accA[i] + xs[i]);
    float y0 = 0.0f, y1 = 0.0f;
#pragma unroll
    for (int f = 0; f < 32; ++f) {
      float h = fmaxf(fmaf(s, sW1[f], sb1[f]), 0.0f);
      y0 = fmaf(h, sW2[2 * f + 0], y0);
      y1 = fmaf(h, sW2[2 * f + 1], y1);
    }
    yd[i] = make_float2(di * y0, di * y1);
  }
}

// ---------------- pass B: accB[dst] += yd[src] (float2) ----------------
__global__ void k_passB(const int* __restrict__ src, const int* __restrict__ dst,
                        int e4, int e, const float2* __restrict__ yd,
                        float* __restrict__ accB) {
  int stride = gridDim.x * blockDim.x;
  const int4* s4 = (const int4*)src;
  const int4* d4 = (const int4*)dst;
  int tid = blockIdx.x * blockDim.x + threadIdx.x;
  for (int i = tid; i < e4; i += stride) {
    int4 s = s4[i];
    int4 d = d4[i];
    float2 v0 = yd[s.x];
    float2 v1 = yd[s.y];
    float2 v2 = yd[s.z];
    float2 v3 = yd[s.w];
    unsafeAtomicAdd(accB + 2 * d.x + 0, v0.x);
    unsafeAtomicAdd(accB + 2 * d.x + 1, v0.y);
    unsafeAtomicAdd(accB + 2 * d.y + 0, v1.x);
    unsafeAtomicAdd(accB + 2 * d.y + 1, v1.y);
    unsafeAtomicAdd(accB + 2 * d.z + 0, v2.x);
    unsafeAtomicAdd(accB + 2 * d.z + 1, v2.y);
    unsafeAtomicAdd(accB + 2 * d.w + 0, v3.x);
    unsafeAtomicAdd(accB + 2 * d.w + 1, v3.y);
  }
  for (int i = e4 * 4 + tid; i < e; i += stride) {
    float2 v = yd[src[i]];
    unsafeAtomicAdd(accB + 2 * dst[i] + 0, v.x);
    unsafeAtomicAdd(accB + 2 * dst[i] + 1, v.y);
  }
}

// ------------- node3: t = dinv*(accB + yd) + b2; log_softmax -------------
__global__ void k_node3(const float* __restrict__ dinv, const float2* __restrict__ yd,
                        const float2* __restrict__ accB, const float* __restrict__ b2,
                        float2* __restrict__ out, int n) {
  float b20 = b2[0], b21 = b2[1];
  int stride = gridDim.x * blockDim.x;
  for (int i = blockIdx.x * blockDim.x + threadIdx.x; i < n; i += stride) {
    float di = dinv[i];
    float2 a = accB[i];
    float2 yv = yd[i];
    float t0 = fmaf(di, a.x + yv.x, b20);
    float t1 = fmaf(di, a.y + yv.y, b21);
    float m = fmaxf(t0, t1);
    float l = m + logf(expf(t0 - m) + expf(t1 - m));
    out[i] = make_float2(t0 - l, t1 - l);
  }
}

extern "C" void kernel_launch(void* const* d_in, const int* in_sizes, int n_in,
                              void* d_out, int out_size, void* d_ws, size_t ws_size,
                              hipStream_t stream) {
  const float* x = (const float*)d_in[0];
  const int* edge = (const int*)d_in[1];   // harness converts integer -> int32
  const float* W1 = (const float*)d_in[2];
  const float* b1 = (const float*)d_in[3];
  const float* W2 = (const float*)d_in[4];
  const float* b2 = (const float*)d_in[5];
  float2* out = (float2*)d_out;

  const int n = in_sizes[0];          // 500000 (x is [N,1])
  const int e = in_sizes[1] / 2;      // 8000000
  const int e4 = e / 4;
  const int* src = edge;
  const int* dst = edge + e;

  // workspace layout (all offsets 8B-aligned)
  char* ws = (char*)d_ws;
  unsigned* deg = (unsigned*)ws;                  // n u32
  float* dinv = (float*)(ws + 1 * (size_t)n * 4); // n f32
  float* xs = (float*)(ws + 2 * (size_t)n * 4);   // n f32
  float* accA = (float*)(ws + 3 * (size_t)n * 4); // n f32
  float2* yd = (float2*)(ws + 4 * (size_t)n * 4); // n f32x2
  float2* accB = (float2*)(ws + 6 * (size_t)n * 4); // n f32x2

  const int node_blk = (n + NT - 1) / NT;
  int edge_blk = (e4 + NT - 1) / NT;
  if (edge_blk > MAX_EDGE_BLK) edge_blk = MAX_EDGE_BLK;

  k_init<<<node_blk, NT, 0, stream>>>(deg, accA, (float2*)accB, n);
  k_degree<<<edge_blk, NT, 0, stream>>>(dst, e4, e, deg);
  k_node1<<<node_blk, NT, 0, stream>>>(deg, x, dinv, xs, n);
  k_passA<<<edge_blk, NT, 0, stream>>>(src, dst, e4, e, xs, accA);
  k_node2<<<node_blk, NT, 0, stream>>>(dinv, xs, accA, W1, b1, W2, yd, n);
  k_passB<<<edge_blk, NT, 0, stream>>>(src, dst, e4, e, yd, (float*)accB);
  k_node3<<<node_blk, NT, 0, stream>>>(dinv, yd, accB, b2, out, n);
}

// Round 2
// 265.392 us; speedup vs baseline: 5.6653x; 5.6653x over previous
//
#include <hip/hip_runtime.h>

// GCN1 on MI355X — zero-global-atomic formulation.
// Round-1 evidence: 32M device-scope atomics ran at ~20.5 G/s (write-through
// 32B/op at the coherence point; WRITE_SIZE 500MB on k_passB) = the entire
// 1.5ms runtime. This version buckets edges by dst (2048 nodes/bucket) with a
// counting sort (LDS histogram + scan + LDS-cursor scatter), then does all
// accumulation with per-bucket LDS atomics and coalesced non-atomic writes.
//
// Algebraic structure (unchanged from round 1, absmax was 3.9e-3):
//   layer1: x is [N,1] -> scalar aggregate s[i]; h1 = relu(s*W1+b1)
//   layer2: only y = h1@W2 (2 wide) needs aggregation.

static constexpr int BKT_BITS = 11;
static constexpr int BKT = 1 << BKT_BITS;  // 2048 nodes per bucket
static constexpr int EB = 1024;            // edge-chunk blocks for hist/scatter
static constexpr int EBT = 256;            // threads for hist/scatter

// ---- 1. per-block histogram of dst buckets ----
__global__ void k_hist(const int* __restrict__ dst, int e, int chunk, int nbkt,
                       unsigned* __restrict__ hist) {
  __shared__ unsigned cnt[256];
  int b = blockIdx.x;
  for (int t = threadIdx.x; t < nbkt; t += blockDim.x) cnt[t] = 0;
  __syncthreads();
  int lo = b * chunk;
  int hi = min(lo + chunk, e);
  for (int i = lo + threadIdx.x; i < hi; i += blockDim.x)
    atomicAdd(&cnt[((unsigned)dst[i]) >> BKT_BITS], 1u);
  __syncthreads();
  for (int t = threadIdx.x; t < nbkt; t += blockDim.x)
    hist[(size_t)b * nbkt + t] = cnt[t];
}

// ---- 2. exclusive scan down each bucket column (1 wave per bucket) ----
__global__ void k_colscan(const unsigned* __restrict__ hist, int nbkt,
                          unsigned* __restrict__ colpre,
                          unsigned* __restrict__ totals) {
  int k = blockIdx.x;
  int lane = threadIdx.x;  // 0..63
  unsigned running = 0;
  for (int c = 0; c < EB; c += 64) {
    unsigned v = hist[(size_t)(c + lane) * nbkt + k];
    unsigned orig = v;
#pragma unroll
    for (int off = 1; off < 64; off <<= 1) {
      unsigned t = __shfl_up(v, off);
      if (lane >= off) v += t;
    }
    colpre[(size_t)(c + lane) * nbkt + k] = running + (v - orig);
    running += __shfl(v, 63);
  }
  if (lane == 0) totals[k] = running;
}

// ---- 3. tiny serial scan over bucket totals ----
__global__ void k_bucketscan(const unsigned* __restrict__ totals, int nbkt,
                             unsigned* __restrict__ base) {
  if (threadIdx.x == 0) {
    unsigned r = 0;
    for (int k = 0; k < nbkt; ++k) {
      base[k] = r;
      r += totals[k];
    }
    base[nbkt] = r;
  }
}

// ---- 4. scatter edges into bucket-grouped packed array ----
__global__ void k_scatter(const int* __restrict__ src, const int* __restrict__ dst,
                          int e, int chunk, int nbkt,
                          const unsigned* __restrict__ colpre,
                          const unsigned* __restrict__ base,
                          unsigned* __restrict__ packed) {
  __shared__ unsigned cur[256];
  int b = blockIdx.x;
  for (int t = threadIdx.x; t < nbkt; t += blockDim.x)
    cur[t] = base[t] + colpre[(size_t)b * nbkt + t];
  __syncthreads();
  int lo = b * chunk;
  int hi = min(lo + chunk, e);
  for (int i = lo + threadIdx.x; i < hi; i += blockDim.x) {
    unsigned d = (unsigned)dst[i];
    unsigned k = d >> BKT_BITS;
    unsigned slot = atomicAdd(&cur[k], 1u);  // LDS atomic — unique slot
    packed[slot] = ((unsigned)src[i] << BKT_BITS) | (d & (BKT - 1));
  }
}

// ---- 5. per-bucket degree count -> dinv, xs = dinv*x ----
__global__ void __launch_bounds__(1024) k_degnode(
    const unsigned* __restrict__ packed, const unsigned* __restrict__ base,
    const float* __restrict__ x, int n, float* __restrict__ dinv,
    float* __restrict__ xs) {
  __shared__ unsigned cnt[BKT];
  int k = blockIdx.x;
  for (int t = threadIdx.x; t < BKT; t += blockDim.x) cnt[t] = 0;
  __syncthreads();
  unsigned lo = base[k], hi = base[k + 1];
  for (unsigned i = lo + threadIdx.x; i < hi; i += blockDim.x)
    atomicAdd(&cnt[packed[i] & (BKT - 1)], 1u);
  __syncthreads();
  int g0 = k << BKT_BITS;
  for (int t = threadIdx.x; t < BKT; t += blockDim.x) {
    int g = g0 + t;
    if (g < n) {
      float di = rsqrtf((float)(cnt[t] + 1u));  // +1 = self-loop
      dinv[g] = di;
      xs[g] = di * x[g];
    }
  }
}

// ---- 6. layer-1 aggregate (LDS) + fused MLP 1->32->2 -> yd = dinv*y ----
__global__ void __launch_bounds__(1024) k_accA2(
    const unsigned* __restrict__ packed, const unsigned* __restrict__ base,
    const float* __restrict__ dinv, const float* __restrict__ xs,
    const float* __restrict__ W1, const float* __restrict__ b1,
    const float* __restrict__ W2, int n, float2* __restrict__ yd) {
  __shared__ float acc[BKT];
  __shared__ float sW1[32], sb1[32], sW2[64];
  if (threadIdx.x < 32) {
    sW1[threadIdx.x] = W1[threadIdx.x];
    sb1[threadIdx.x] = b1[threadIdx.x];
  } else if (threadIdx.x < 96) {
    sW2[threadIdx.x - 32] = W2[threadIdx.x - 32];
  }
  for (int t = threadIdx.x; t < BKT; t += blockDim.x) acc[t] = 0.0f;
  __syncthreads();
  int k = blockIdx.x;
  unsigned lo = base[k], hi = base[k + 1];
  for (unsigned i = lo + threadIdx.x; i < hi; i += blockDim.x) {
    unsigned p = packed[i];
    atomicAdd(&acc[p & (BKT - 1)], xs[p >> BKT_BITS]);
  }
  __syncthreads();
  int g0 = k << BKT_BITS;
  for (int t = threadIdx.x; t < BKT; t += blockDim.x) {
    int g = g0 + t;
    if (g >= n) continue;
    float di = dinv[g];
    float s = di * (acc[t] + xs[g]);  // self-loop: dinv^2*x = dinv*xs
    float y0 = 0.0f, y1 = 0.0f;
#pragma unroll
    for (int f = 0; f < 32; ++f) {
      float h = fmaxf(fmaf(s, sW1[f], sb1[f]), 0.0f);
      y0 = fmaf(h, sW2[2 * f + 0], y0);
      y1 = fmaf(h, sW2[2 * f + 1], y1);
    }
    yd[g] = make_float2(di * y0, di * y1);
  }
}

// ---- 7. layer-2 aggregate (LDS float2) + fused log-softmax ----
__global__ void __launch_bounds__(1024) k_accB3(
    const unsigned* __restrict__ packed, const unsigned* __restrict__ base,
    const float* __restrict__ dinv, const float2* __restrict__ yd,
    const float* __restrict__ b2, int n, float2* __restrict__ out) {
  __shared__ float a0[BKT], a1[BKT];
  for (int t = threadIdx.x; t < BKT; t += blockDim.x) {
    a0[t] = 0.0f;
    a1[t] = 0.0f;
  }
  __syncthreads();
  int k = blockIdx.x;
  unsigned lo = base[k], hi = base[k + 1];
  for (unsigned i = lo + threadIdx.x; i < hi; i += blockDim.x) {
    unsigned p = packed[i];
    float2 v = yd[p >> BKT_BITS];
    unsigned l = p & (BKT - 1);
    atomicAdd(&a0[l], v.x);
    atomicAdd(&a1[l], v.y);
  }
  __syncthreads();
  float b20 = b2[0], b21 = b2[1];
  int g0 = k << BKT_BITS;
  for (int t = threadIdx.x; t < BKT; t += blockDim.x) {
    int g = g0 + t;
    if (g >= n) continue;
    float di = dinv[g];
    float2 yv = yd[g];
    float t0 = fmaf(di, a0[t] + yv.x, b20);
    float t1 = fmaf(di, a1[t] + yv.y, b21);
    float m = fmaxf(t0, t1);
    float l2 = m + logf(expf(t0 - m) + expf(t1 - m));
    out[g] = make_float2(t0 - l2, t1 - l2);
  }
}

extern "C" void kernel_launch(void* const* d_in, const int* in_sizes, int n_in,
                              void* d_out, int out_size, void* d_ws, size_t ws_size,
                              hipStream_t stream) {
  const float* x = (const float*)d_in[0];
  const int* edge = (const int*)d_in[1];  // harness converts int64 -> int32
  const float* W1 = (const float*)d_in[2];
  const float* b1 = (const float*)d_in[3];
  const float* W2 = (const float*)d_in[4];
  const float* b2 = (const float*)d_in[5];
  float2* out = (float2*)d_out;

  const int n = in_sizes[0];      // 500000
  const int e = in_sizes[1] / 2;  // 8000000
  const int* src = edge;
  const int* dst = edge + e;

  const int nbkt = (n + BKT - 1) >> BKT_BITS;  // 245
  const int chunk = (e + EB - 1) / EB;         // 7813

  // ---- workspace layout (all region starts 8B-aligned) ----
  // packed: e u32                                  [phases 4..7]
  // base:   (nbkt+1) u32 (+pad)                    [phases 3..7]
  // dinv:   n f32                                  [5..7]
  // xs:     n f32                                  [5..6]
  // region B (overlay): { hist EB*nbkt u32 | colpre EB*nbkt u32 | totals }
  //                     [1..4]  reused as  yd: n float2  [6..7]
  char* ws = (char*)d_ws;
  size_t off = 0;
  unsigned* packed = (unsigned*)(ws + off);
  off += (size_t)e * 4;
  unsigned* base = (unsigned*)(ws + off);
  off += ((size_t)(nbkt + 1) * 4 + 255) & ~(size_t)255;
  float* dinv = (float*)(ws + off);
  off += (size_t)n * 4;
  float* xs = (float*)(ws + off);
  off += (size_t)n * 4;
  size_t offB = off;
  unsigned* hist = (unsigned*)(ws + offB);
  unsigned* colpre = (unsigned*)(ws + offB + (size_t)EB * nbkt * 4);
  unsigned* totals = (unsigned*)(ws + offB + 2 * (size_t)EB * nbkt * 4);
  float2* yd = (float2*)(ws + offB);  // overlays hist/colpre/totals (dead by phase 6)

  k_hist<<<EB, EBT, 0, stream>>>(dst, e, chunk, nbkt, hist);
  k_colscan<<<nbkt, 64, 0, stream>>>(hist, nbkt, colpre, totals);
  k_bucketscan<<<1, 64, 0, stream>>>(totals, nbkt, base);
  k_scatter<<<EB, EBT, 0, stream>>>(src, dst, e, chunk, nbkt, colpre, base, packed);
  k_degnode<<<nbkt, 1024, 0, stream>>>(packed, base, x, n, dinv, xs);
  k_accA2<<<nbkt, 1024, 0, stream>>>(packed, base, dinv, xs, W1, b1, W2, n, yd);
  k_accB3<<<nbkt, 1024, 0, stream>>>(packed, base, dinv, yd, b2, n, out);
}

// Round 3
// 236.331 us; speedup vs baseline: 6.3619x; 1.1230x over previous
//
#include <hip/hip_runtime.h>

// GCN1 on MI355X. Round-2 evidence: k_scatter wrote 180MB for a 32MB packed
// array (5.6x write amp — partial-line dribble over the block's lifetime).
// Round-3: block-local full counting sort (regs + 32KB LDS staged buffer),
// then LINEAR copy-out -> bursty near-1x writes. Global placement via one
// atomicAdd per (block,bucket) on 245 cursors (replaces colscan/bucketscan).
//
// Algebra (validated rounds 1-2, absmax 3.9e-3):
//   layer1: x is [N,1] -> scalar aggregate s[i]; h1 = relu(s*W1+b1)
//   layer2: only y = h1@W2 (2-wide) aggregates; epilogues fused.

static constexpr int BKT_BITS = 11;
static constexpr int BKT = 1 << BKT_BITS;  // 2048 nodes/bucket
static constexpr int NB = 256;             // padded bucket count (nbkt=245)
static constexpr int HB = 512;             // hist blocks
static constexpr int HT = 256;
static constexpr int CHUNK = 8192;         // edges per scatter block
static constexpr int SCT = 256;
static constexpr int PERT = CHUNK / SCT;   // 32 edges/thread in registers

// ---- 1. per-bucket totals: LDS histogram, one global add per bucket ----
__global__ void __launch_bounds__(HT) k_hist(const int* __restrict__ dst, int e,
                                             int chunk, int nbkt,
                                             unsigned* __restrict__ totals) {
  __shared__ unsigned cnt[NB];
  for (int t = threadIdx.x; t < NB; t += HT) cnt[t] = 0;
  __syncthreads();
  int lo = blockIdx.x * chunk;           // chunk is a multiple of 4
  int hi = min(lo + chunk, e);
  const int4* d4 = (const int4*)dst;
  for (int i = (lo >> 2) + threadIdx.x; i < (hi >> 2); i += HT) {
    int4 d = d4[i];
    atomicAdd(&cnt[((unsigned)d.x) >> BKT_BITS], 1u);
    atomicAdd(&cnt[((unsigned)d.y) >> BKT_BITS], 1u);
    atomicAdd(&cnt[((unsigned)d.z) >> BKT_BITS], 1u);
    atomicAdd(&cnt[((unsigned)d.w) >> BKT_BITS], 1u);
  }
  for (int i = ((hi >> 2) << 2) + threadIdx.x; i < hi; i += HT)  // tail
    atomicAdd(&cnt[((unsigned)dst[i]) >> BKT_BITS], 1u);
  __syncthreads();
  for (int t = threadIdx.x; t < nbkt; t += HT)
    if (cnt[t]) atomicAdd(&totals[t], cnt[t]);
}

// ---- 2. exclusive scan of totals -> gcur (single wave) ----
__global__ void k_basescan(const unsigned* __restrict__ totals, int nbkt,
                           unsigned* __restrict__ gcur) {
  int lane = threadIdx.x;  // blockDim = 64
  unsigned running = 0;
  for (int c = 0; c < NB; c += 64) {
    int k = c + lane;
    unsigned v = (k < nbkt) ? totals[k] : 0u;
    unsigned incl = v;
#pragma unroll
    for (int off = 1; off < 64; off <<= 1) {
      unsigned t = __shfl_up(incl, off);
      if (lane >= off) incl += t;
    }
    if (k < nbkt) gcur[k] = running + incl - v;
    running += __shfl(incl, 63);
  }
}

// ---- 3. scatter: block-local counting sort + linear copy-out ----
__global__ void __launch_bounds__(SCT) k_scatter(
    const int* __restrict__ src, const int* __restrict__ dst, int e, int nbkt,
    unsigned* __restrict__ gcur, unsigned* __restrict__ packed) {
  __shared__ unsigned staged[CHUNK];  // 32 KB, bucket-sorted chunk
  __shared__ unsigned cnt[NB];
  __shared__ unsigned cur[NB];
  __shared__ unsigned gseg[NB];
  __shared__ unsigned loff[NB + 1];
  const int tid = threadIdx.x;
  const int lo = blockIdx.x * CHUNK;
  for (int t = tid; t < NB; t += SCT) { cnt[t] = 0u; cur[t] = 0u; }
  __syncthreads();

  unsigned pk[PERT];       // (src<<11)|dst_local
  unsigned bku[PERT / 4];  // 4 bucket ids per u32 (nbkt=245 fits u8; 0xFF=invalid)
  const int4* s4 = (const int4*)src;
  const int4* d4 = (const int4*)dst;
#pragma unroll
  for (int jj = 0; jj < PERT / 4; ++jj) {
    int i4 = (lo >> 2) + jj * SCT + tid;
    unsigned b4 = 0xFFFFFFFFu;
    if (i4 * 4 + 3 < e) {
      int4 s = s4[i4];
      int4 d = d4[i4];
      unsigned k0 = ((unsigned)d.x) >> BKT_BITS, k1 = ((unsigned)d.y) >> BKT_BITS;
      unsigned k2 = ((unsigned)d.z) >> BKT_BITS, k3 = ((unsigned)d.w) >> BKT_BITS;
      pk[jj * 4 + 0] = ((unsigned)s.x << BKT_BITS) | ((unsigned)d.x & (BKT - 1));
      pk[jj * 4 + 1] = ((unsigned)s.y << BKT_BITS) | ((unsigned)d.y & (BKT - 1));
      pk[jj * 4 + 2] = ((unsigned)s.z << BKT_BITS) | ((unsigned)d.z & (BKT - 1));
      pk[jj * 4 + 3] = ((unsigned)s.w << BKT_BITS) | ((unsigned)d.w & (BKT - 1));
      b4 = k0 | (k1 << 8) | (k2 << 16) | (k3 << 24);
      atomicAdd(&cnt[k0], 1u);
      atomicAdd(&cnt[k1], 1u);
      atomicAdd(&cnt[k2], 1u);
      atomicAdd(&cnt[k3], 1u);
    } else {
#pragma unroll
      for (int c = 0; c < 4; ++c) {
        int i = i4 * 4 + c;
        if (i >= lo && i < e) {
          unsigned dd = (unsigned)dst[i];
          unsigned kk = dd >> BKT_BITS;
          pk[jj * 4 + c] = ((unsigned)src[i] << BKT_BITS) | (dd & (BKT - 1));
          b4 = (b4 & ~(0xFFu << (8 * c))) | (kk << (8 * c));
          atomicAdd(&cnt[kk], 1u);
        }
      }
    }
    bku[jj] = b4;
  }
  __syncthreads();

  // exclusive scan cnt -> loff (wave 0)
  if (tid < 64) {
    unsigned running = 0;
    for (int c = 0; c < NB; c += 64) {
      int k = c + tid;
      unsigned v = cnt[k];
      unsigned incl = v;
#pragma unroll
      for (int off = 1; off < 64; off <<= 1) {
        unsigned t = __shfl_up(incl, off);
        if (tid >= off) incl += t;
      }
      loff[k] = running + incl - v;
      running += __shfl(incl, 63);
    }
    if (tid == 0) loff[NB] = running;
  }
  __syncthreads();

  // reserve global segments: one atomic per non-empty bucket
  for (int k = tid; k < nbkt; k += SCT)
    if (cnt[k]) gseg[k] = atomicAdd(&gcur[k], cnt[k]);

  // place into staged (bucket-sorted order)
#pragma unroll
  for (int jj = 0; jj < PERT / 4; ++jj) {
    unsigned b4 = bku[jj];
#pragma unroll
    for (int c = 0; c < 4; ++c) {
      unsigned k = (b4 >> (8 * c)) & 0xFFu;
      if (k != 0xFFu) {
        unsigned pos = loff[k] + atomicAdd(&cur[k], 1u);
        staged[pos] = pk[jj * 4 + c];
      }
    }
  }
  __syncthreads();

  // linear copy-out; binary search bucket id in LDS
  int mv = (int)loff[nbkt];
  for (int t = tid; t < mv; t += SCT) {
    int a = 0, b = nbkt;  // invariant: loff[a] <= t < loff[b]
    while (b - a > 1) {
      int mid = (a + b) >> 1;
      if ((int)loff[mid] <= t) a = mid; else b = mid;
    }
    packed[gseg[a] + (unsigned)(t - (int)loff[a])] = staged[t];
  }
}

// ---- 4. per-bucket degree -> dinv, xs = dinv*x ----
__global__ void __launch_bounds__(1024) k_degnode(
    const unsigned* __restrict__ packed, const unsigned* __restrict__ gcur,
    const float* __restrict__ x, int n, float* __restrict__ dinv,
    float* __restrict__ xs) {
  __shared__ unsigned cnt[BKT];
  int k = blockIdx.x;
  for (int t = threadIdx.x; t < BKT; t += blockDim.x) cnt[t] = 0;
  __syncthreads();
  unsigned lo = k ? gcur[k - 1] : 0u, hi = gcur[k];
  for (unsigned i = lo + threadIdx.x; i < hi; i += blockDim.x)
    atomicAdd(&cnt[packed[i] & (BKT - 1)], 1u);
  __syncthreads();
  int g0 = k << BKT_BITS;
  for (int t = threadIdx.x; t < BKT; t += blockDim.x) {
    int g = g0 + t;
    if (g < n) {
      float di = rsqrtf((float)(cnt[t] + 1u));  // +1 self-loop
      dinv[g] = di;
      xs[g] = di * x[g];
    }
  }
}

// ---- 5. layer-1 aggregate + fused MLP 1->32->2 -> yd = dinv*y ----
__global__ void __launch_bounds__(1024) k_accA2(
    const unsigned* __restrict__ packed, const unsigned* __restrict__ gcur,
    const float* __restrict__ dinv, const float* __restrict__ xs,
    const float* __restrict__ W1, const float* __restrict__ b1,
    const float* __restrict__ W2, int n, float2* __restrict__ yd) {
  __shared__ float acc[BKT];
  __shared__ float sW1[32], sb1[32], sW2[64];
  if (threadIdx.x < 32) {
    sW1[threadIdx.x] = W1[threadIdx.x];
    sb1[threadIdx.x] = b1[threadIdx.x];
  } else if (threadIdx.x < 96) {
    sW2[threadIdx.x - 32] = W2[threadIdx.x - 32];
  }
  for (int t = threadIdx.x; t < BKT; t += blockDim.x) acc[t] = 0.0f;
  __syncthreads();
  int k = blockIdx.x;
  unsigned lo = k ? gcur[k - 1] : 0u, hi = gcur[k];
  for (unsigned i = lo + threadIdx.x; i < hi; i += blockDim.x) {
    unsigned p = packed[i];
    atomicAdd(&acc[p & (BKT - 1)], xs[p >> BKT_BITS]);
  }
  __syncthreads();
  int g0 = k << BKT_BITS;
  for (int t = threadIdx.x; t < BKT; t += blockDim.x) {
    int g = g0 + t;
    if (g >= n) continue;
    float di = dinv[g];
    float s = di * (acc[t] + xs[g]);  // self-loop: dinv^2*x = dinv*xs
    float y0 = 0.0f, y1 = 0.0f;
#pragma unroll
    for (int f = 0; f < 32; ++f) {
      float h = fmaxf(fmaf(s, sW1[f], sb1[f]), 0.0f);
      y0 = fmaf(h, sW2[2 * f + 0], y0);
      y1 = fmaf(h, sW2[2 * f + 1], y1);
    }
    yd[g] = make_float2(di * y0, di * y1);
  }
}

// ---- 6. layer-2 aggregate + fused log-softmax ----
__global__ void __launch_bounds__(1024) k_accB3(
    const unsigned* __restrict__ packed, const unsigned* __restrict__ gcur,
    const float* __restrict__ dinv, const float2* __restrict__ yd,
    const float* __restrict__ b2, int n, float2* __restrict__ out) {
  __shared__ float a0[BKT], a1[BKT];
  for (int t = threadIdx.x; t < BKT; t += blockDim.x) {
    a0[t] = 0.0f;
    a1[t] = 0.0f;
  }
  __syncthreads();
  int k = blockIdx.x;
  unsigned lo = k ? gcur[k - 1] : 0u, hi = gcur[k];
  for (unsigned i = lo + threadIdx.x; i < hi; i += blockDim.x) {
    unsigned p = packed[i];
    float2 v = yd[p >> BKT_BITS];
    unsigned l = p & (BKT - 1);
    atomicAdd(&a0[l], v.x);
    atomicAdd(&a1[l], v.y);
  }
  __syncthreads();
  float b20 = b2[0], b21 = b2[1];
  int g0 = k << BKT_BITS;
  for (int t = threadIdx.x; t < BKT; t += blockDim.x) {
    int g = g0 + t;
    if (g >= n) continue;
    float di = dinv[g];
    float2 yv = yd[g];
    float t0 = fmaf(di, a0[t] + yv.x, b2[0] * 0.0f + b20);
    float t1 = fmaf(di, a1[t] + yv.y, b21);
    float m = fmaxf(t0, t1);
    float l2 = m + logf(expf(t0 - m) + expf(t1 - m));
    out[g] = make_float2(t0 - l2, t1 - l2);
  }
}

extern "C" void kernel_launch(void* const* d_in, const int* in_sizes, int n_in,
                              void* d_out, int out_size, void* d_ws, size_t ws_size,
                              hipStream_t stream) {
  const float* x = (const float*)d_in[0];
  const int* edge = (const int*)d_in[1];  // int64 inputs arrive as int32
  const float* W1 = (const float*)d_in[2];
  const float* b1 = (const float*)d_in[3];
  const float* W2 = (const float*)d_in[4];
  const float* b2 = (const float*)d_in[5];
  float2* out = (float2*)d_out;

  const int n = in_sizes[0];      // 500000
  const int e = in_sizes[1] / 2;  // 8000000
  const int* src = edge;
  const int* dst = edge + e;

  const int nbkt = (n + BKT - 1) >> BKT_BITS;            // 245
  const int hchunk = (((e + HB - 1) / HB) + 3) & ~3;     // mult of 4
  const int sgrid = (e + CHUNK - 1) / CHUNK;             // 977

  // ---- workspace ----
  char* ws = (char*)d_ws;
  unsigned* packed = (unsigned*)ws;                      // e u32   (32 MB)
  unsigned* totals = (unsigned*)(ws + (size_t)e * 4);    // NB u32
  unsigned* gcur = totals + NB;                          // NB u32 (base, then end cursors)
  float* dinv = (float*)(gcur + NB);                     // n f32
  float* xs = dinv + n;                                  // n f32
  float2* yd = (float2*)(xs + n);                        // n float2

  hipMemsetAsync(totals, 0, NB * sizeof(unsigned), stream);
  k_hist<<<HB, HT, 0, stream>>>(dst, e, hchunk, nbkt, totals);
  k_basescan<<<1, 64, 0, stream>>>(totals, nbkt, gcur);
  k_scatter<<<sgrid, SCT, 0, stream>>>(src, dst, e, nbkt, gcur, packed);
  // after k_scatter: gcur[k] == end of bucket k (== start of bucket k+1)
  k_degnode<<<nbkt, 1024, 0, stream>>>(packed, gcur, x, n, dinv, xs);
  k_accA2<<<nbkt, 1024, 0, stream>>>(packed, gcur, dinv, xs, W1, b1, W2, n, yd);
  k_accB3<<<nbkt, 1024, 0, stream>>>(packed, gcur, dinv, yd, b2, n, out);
}